// Round 9
// baseline (538.879 us; speedup 1.0000x reference)
//
#include <hip/hip_runtime.h>
#include <hip/hip_bf16.h>
#include <stdint.h>

// MHA forward: B=4, S=2048, D=512, H=8, HD=64. f32 in/out, bf16 MFMA internally.
// out0 = out [B,S,D] f32, out1 = attn [B,H,S,S] f32 (concatenated in d_out).
// Split design: k_proj_qkv -> k_attn_o (O + softmax denominators, no attn
// store) -> k_proj_out -> k_attn_wr (recompute QK^T, pure attn store stream).

typedef __attribute__((ext_vector_type(8))) short bf16x8;
typedef __attribute__((ext_vector_type(4))) short bf16x4;
typedef __attribute__((ext_vector_type(4))) float f32x4;

#define MFMA16(a, b, c) __builtin_amdgcn_mfma_f32_16x16x32_bf16((a), (b), (c), 0, 0, 0)

__device__ __forceinline__ unsigned short f2bf(float f) {
  unsigned u = __float_as_uint(f);
  u += 0x7FFFu + ((u >> 16) & 1u);   // RNE
  return (unsigned short)(u >> 16);
}
__device__ __forceinline__ float bf2f(unsigned short u) {
  return __uint_as_float(((unsigned)u) << 16);
}

// ---------------------------------------------------------------------------
// Kernel 1: fused QKV projection. z = 0,1,2 -> q,k,v.
// q,k written as [B,H,S,HD] bf16; v written transposed [B,H,HD,S] bf16.
// ---------------------------------------------------------------------------
__global__ __launch_bounds__(256) void k_proj_qkv(
    const float* __restrict__ q_in, const float* __restrict__ k_in,
    const float* __restrict__ v_in,
    const float* __restrict__ Wq, const float* __restrict__ bq,
    const float* __restrict__ Wk, const float* __restrict__ bk,
    const float* __restrict__ Wv, const float* __restrict__ bv,
    unsigned short* __restrict__ q_ws, unsigned short* __restrict__ k_ws,
    unsigned short* __restrict__ vt_ws)
{
  const int z = blockIdx.z;
  const float* X    = (z == 0) ? q_in : (z == 1) ? k_in : v_in;
  const float* W    = (z == 0) ? Wq   : (z == 1) ? Wk   : Wv;
  const float* bias = (z == 0) ? bq   : (z == 1) ? bk   : bv;
  unsigned short* out = (z == 0) ? q_ws : (z == 1) ? k_ws : vt_ws;

  __shared__ unsigned short As[128][72];
  __shared__ unsigned short Bs[128][72];

  const int t = threadIdx.x;
  const int lane = t & 63;
  const int w = t >> 6;
  const int wr = w >> 1, wc = w & 1;
  const int mbase = blockIdx.x * 128;
  const int nbase = blockIdx.y * 128;

  f32x4 acc[4][4] = {};

  for (int kb = 0; kb < 512; kb += 64) {
    __syncthreads();
#pragma unroll
    for (int i = 0; i < 4; ++i) {
      int chunk = i * 256 + t;
      int row = chunk >> 3;
      int c8 = (chunk & 7) * 8;
      const float* ga = X + (size_t)(mbase + row) * 512 + kb + c8;
      float4 a0 = *(const float4*)ga;
      float4 a1 = *(const float4*)(ga + 4);
      bf16x8 pa;
      pa[0] = (short)f2bf(a0.x); pa[1] = (short)f2bf(a0.y);
      pa[2] = (short)f2bf(a0.z); pa[3] = (short)f2bf(a0.w);
      pa[4] = (short)f2bf(a1.x); pa[5] = (short)f2bf(a1.y);
      pa[6] = (short)f2bf(a1.z); pa[7] = (short)f2bf(a1.w);
      *(bf16x8*)&As[row][c8] = pa;
      const float* gb = W + (size_t)(nbase + row) * 512 + kb + c8;
      float4 b0 = *(const float4*)gb;
      float4 b1 = *(const float4*)(gb + 4);
      bf16x8 pb;
      pb[0] = (short)f2bf(b0.x); pb[1] = (short)f2bf(b0.y);
      pb[2] = (short)f2bf(b0.z); pb[3] = (short)f2bf(b0.w);
      pb[4] = (short)f2bf(b1.x); pb[5] = (short)f2bf(b1.y);
      pb[6] = (short)f2bf(b1.z); pb[7] = (short)f2bf(b1.w);
      *(bf16x8*)&Bs[row][c8] = pb;
    }
    __syncthreads();
#pragma unroll
    for (int kk = 0; kk < 64; kk += 32) {
      bf16x8 af[4], bfr[4];
#pragma unroll
      for (int mi = 0; mi < 4; ++mi)
        af[mi] = *(const bf16x8*)&As[wr * 64 + mi * 16 + (lane & 15)][kk + (lane >> 4) * 8];
#pragma unroll
      for (int ni = 0; ni < 4; ++ni)
        bfr[ni] = *(const bf16x8*)&Bs[wc * 64 + ni * 16 + (lane & 15)][kk + (lane >> 4) * 8];
#pragma unroll
      for (int mi = 0; mi < 4; ++mi)
#pragma unroll
        for (int ni = 0; ni < 4; ++ni)
          acc[mi][ni] = MFMA16(af[mi], bfr[ni], acc[mi][ni]);
    }
  }

#pragma unroll
  for (int ni = 0; ni < 4; ++ni) {
    int n = nbase + wc * 64 + ni * 16 + (lane & 15);
    float bv_ = bias[n];
    int h = n >> 6, hd = n & 63;
#pragma unroll
    for (int mi = 0; mi < 4; ++mi) {
#pragma unroll
      for (int i = 0; i < 4; ++i) {
        int m = mbase + wr * 64 + mi * 16 + (lane >> 4) * 4 + i;
        int b_ = m >> 11, s = m & 2047;
        float val = acc[mi][ni][i] + bv_;
        size_t off;
        if (z < 2) off = ((size_t)(b_ * 8 + h) * 2048 + s) * 64 + hd;      // [B,H,S,HD]
        else       off = ((size_t)(b_ * 8 + h) * 64 + hd) * 2048 + s;      // [B,H,HD,S]
        out[off] = f2bf(val);
      }
    }
  }
}

// ---------------------------------------------------------------------------
// Kernel 2a: attention O + denominators. Block = (b,h) x 16 q-rows, 8 waves.
// Wave w owns k-cols [w*256..+256). Swapped QK^T: mfma(K,Q) -> lane (lo=q,hi)
// holds 4 consecutive k for its q row. No attn stores here.
// ---------------------------------------------------------------------------
__global__ __launch_bounds__(512) void k_attn_o(
    const unsigned short* __restrict__ q_ws, const unsigned short* __restrict__ k_ws,
    const unsigned short* __restrict__ vt_ws, unsigned short* __restrict__ o_ws,
    float* __restrict__ rinv_g)
{
  __shared__ float o_red[8][16][68];            // per-wave O partials (+4 pad)
  __shared__ float wsum[8][16];
  __shared__ float rinv_s[16];

  const int t = threadIdx.x;
  const int lane = t & 63;
  const int w = t >> 6;            // 0..7
  const int lo = lane & 15;
  const int hi = lane >> 4;        // 0..3
  const int bh = blockIdx.y;       // 0..31
  const int qbase = blockIdx.x * 16;
  const size_t qk_base = (size_t)bh * 2048 * 64;
  const int kw = w * 256;          // wave's k range

  // Q fragments (B operand: col = q = lo, d = hi*8 + j)
  bf16x8 qf0 = *(const bf16x8*)(q_ws + qk_base + (size_t)(qbase + lo) * 64 + hi * 8);
  bf16x8 qf1 = *(const bf16x8*)(q_ws + qk_base + (size_t)(qbase + lo) * 64 + 32 + hi * 8);

  unsigned p_pk[16][2];            // packed bf16 pairs: k = t2*16 + hi*4 + (0..3), q = lo
  float srow = 0.f;

  // --- Phase 1: QK^T -> exp -> packed regs + row-sum partials ---
#pragma unroll
  for (int t2 = 0; t2 < 16; ++t2) {
    const int cb = kw + t2 * 16;
    const unsigned short* kp = k_ws + qk_base + (size_t)(cb + lo) * 64 + hi * 8;
    bf16x8 kf0 = *(const bf16x8*)kp;
    bf16x8 kf1 = *(const bf16x8*)(kp + 32);
    f32x4 c = {};
    c = MFMA16(kf0, qf0, c);
    c = MFMA16(kf1, qf1, c);
    float e0 = __expf(c[0] * 0.125f);
    float e1 = __expf(c[1] * 0.125f);
    float e2 = __expf(c[2] * 0.125f);
    float e3 = __expf(c[3] * 0.125f);
    srow += (e0 + e1) + (e2 + e3);
    p_pk[t2][0] = (unsigned)f2bf(e0) | ((unsigned)f2bf(e1) << 16);
    p_pk[t2][1] = (unsigned)f2bf(e2) | ((unsigned)f2bf(e3) << 16);
  }

  // --- Phase 2: denominator; also publish to global for the writer kernel ---
  srow += __shfl_xor(srow, 16, 64);
  srow += __shfl_xor(srow, 32, 64);
  if (hi == 0) wsum[w][lo] = srow;
  __syncthreads();
  if (t < 16) {
    float s = 0.f;
#pragma unroll
    for (int ww = 0; ww < 8; ++ww) s += wsum[ww][t];
    float r = 1.0f / s;
    rinv_s[t] = r;
    rinv_g[(size_t)bh * 2048 + qbase + t] = r;
  }
  __syncthreads();
  const float rv = rinv_s[lo];

  // --- Phase 3: PV MFMA with normalized P ---
  f32x4 o_acc[4] = {};             // [hd-tile]: rows q = hi*4+i, col hd = hdt*16+lo
  {
#pragma unroll
    for (int tp = 0; tp < 8; ++tp) {
      const int cb = kw + tp * 32;
      unsigned a0 = p_pk[2 * tp][0], a1 = p_pk[2 * tp][1];
      unsigned b0 = p_pk[2 * tp + 1][0], b1 = p_pk[2 * tp + 1][1];
      bf16x8 pa8;
      pa8[0] = (short)f2bf(bf2f((unsigned short)(a0 & 0xffffu)) * rv);
      pa8[1] = (short)f2bf(bf2f((unsigned short)(a0 >> 16)) * rv);
      pa8[2] = (short)f2bf(bf2f((unsigned short)(a1 & 0xffffu)) * rv);
      pa8[3] = (short)f2bf(bf2f((unsigned short)(a1 >> 16)) * rv);
      pa8[4] = (short)f2bf(bf2f((unsigned short)(b0 & 0xffffu)) * rv);
      pa8[5] = (short)f2bf(bf2f((unsigned short)(b0 >> 16)) * rv);
      pa8[6] = (short)f2bf(bf2f((unsigned short)(b1 & 0xffffu)) * rv);
      pa8[7] = (short)f2bf(bf2f((unsigned short)(b1 >> 16)) * rv);
#pragma unroll
      for (int hdt = 0; hdt < 4; ++hdt) {
        const unsigned short* vp = vt_ws +
            (size_t)(bh * 64 + hdt * 16 + lo) * 2048 + cb + hi * 4;
        bf16x4 v4a = *(const bf16x4*)vp;
        bf16x4 v4b = *(const bf16x4*)(vp + 16);
        bf16x8 vb8;
        vb8[0] = v4a[0]; vb8[1] = v4a[1]; vb8[2] = v4a[2]; vb8[3] = v4a[3];
        vb8[4] = v4b[0]; vb8[5] = v4b[1]; vb8[6] = v4b[2]; vb8[7] = v4b[3];
        o_acc[hdt] = MFMA16(pa8, vb8, o_acc[hdt]);
      }
    }
  }

  // --- Phase 4: O reduce across waves + write (already normalized) ---
#pragma unroll
  for (int hdt = 0; hdt < 4; ++hdt)
#pragma unroll
    for (int i = 0; i < 4; ++i)
      o_red[w][hi * 4 + i][hdt * 16 + lo] = o_acc[hdt][i];
  __syncthreads();
  {
    const int b_ = bh >> 3, h = bh & 7;
#pragma unroll
    for (int e = 0; e < 2; ++e) {
      int idx = t + e * 512;       // 0..1023 over [16 q][64 hd]
      int q = idx >> 6, hd = idx & 63;
      float s = 0.f;
#pragma unroll
      for (int ww = 0; ww < 8; ++ww) s += o_red[ww][q][hd];
      o_ws[((size_t)(b_ * 2048) + qbase + q) * 512 + h * 64 + hd] = f2bf(s);
    }
  }
}

// ---------------------------------------------------------------------------
// Kernel 2b: attn writer. Pure store-stream kernel: recompute swapped QK^T
// from L2-resident Q/K, normalize with rinv_g, bounce through a wave-private
// LDS tile, then nontemporal f32x4 stores in 512B-contiguous runs.
// Block = 256 thr (4 waves); wave w owns kv [w*512, +512). No barriers.
// ---------------------------------------------------------------------------
__global__ __launch_bounds__(256) void k_attn_wr(
    const unsigned short* __restrict__ q_ws, const unsigned short* __restrict__ k_ws,
    const float* __restrict__ rinv_g, float* __restrict__ attn_out)
{
  __shared__ float pst[4][16][131];   // per-wave tile: 16 rows x 128 cols (+3 pad)

  const int t = threadIdx.x;
  const int lane = t & 63;
  const int w = t >> 6;            // 0..3
  const int lo = lane & 15;
  const int hi = lane >> 4;        // 0..3
  const int bh = blockIdx.y;       // 0..31
  const int qbase = blockIdx.x * 16;
  const size_t qk_base = (size_t)bh * 2048 * 64;
  const int kw = w * 512;          // wave's k range

  bf16x8 qf0 = *(const bf16x8*)(q_ws + qk_base + (size_t)(qbase + lo) * 64 + hi * 8);
  bf16x8 qf1 = *(const bf16x8*)(q_ws + qk_base + (size_t)(qbase + lo) * 64 + 32 + hi * 8);
  const float rv = rinv_g[(size_t)bh * 2048 + qbase + lo];

  float* ao = attn_out + (size_t)bh * 2048 * 2048 + (size_t)qbase * 2048;
  const int r2 = lane >> 5;        // 0..1
  const int c4 = lane & 31;        // 0..31

  for (int g = 0; g < 4; ++g) {    // 4 groups of 128 kv per wave
#pragma unroll
    for (int t2 = 0; t2 < 8; ++t2) {
      const int cb = kw + g * 128 + t2 * 16;
      const unsigned short* kp = k_ws + qk_base + (size_t)(cb + lo) * 64 + hi * 8;
      bf16x8 kf0 = *(const bf16x8*)kp;
      bf16x8 kf1 = *(const bf16x8*)(kp + 32);
      f32x4 c = {};
      c = MFMA16(kf0, qf0, c);
      c = MFMA16(kf1, qf1, c);
      f32x4 s;
      s[0] = __expf(c[0] * 0.125f) * rv;
      s[1] = __expf(c[1] * 0.125f) * rv;
      s[2] = __expf(c[2] * 0.125f) * rv;
      s[3] = __expf(c[3] * 0.125f) * rv;
      *(f32x4*)&pst[w][lo][t2 * 16 + hi * 4] = s;   // row = q (lo), col = kv
    }
    // transpose read: instr i covers rows 2i,2i+1 x 128 cols -> 2x512B runs
#pragma unroll
    for (int i = 0; i < 8; ++i) {
      int row = 2 * i + r2;
      f32x4 v = *(const f32x4*)&pst[w][row][c4 * 4];
      __builtin_nontemporal_store(
          v, (f32x4*)(ao + (size_t)row * 2048 + kw + g * 128 + c4 * 4));
    }
  }
}

// ---------------------------------------------------------------------------
// Kernel 3: output projection, f32 out.
// ---------------------------------------------------------------------------
__global__ __launch_bounds__(256) void k_proj_out(
    const unsigned short* __restrict__ Ao, const float* __restrict__ Wo,
    const float* __restrict__ bo, float* __restrict__ outp)
{
  __shared__ unsigned short As[128][72];
  __shared__ unsigned short Bs[128][72];

  const int t = threadIdx.x;
  const int lane = t & 63;
  const int w = t >> 6;
  const int wr = w >> 1, wc = w & 1;
  const int mbase = blockIdx.x * 128;
  const int nbase = blockIdx.y * 128;

  f32x4 acc[4][4] = {};

  for (int kb = 0; kb < 512; kb += 64) {
    __syncthreads();
#pragma unroll
    for (int i = 0; i < 4; ++i) {
      int chunk = i * 256 + t;
      int row = chunk >> 3;
      int c8 = (chunk & 7) * 8;
      *(bf16x8*)&As[row][c8] =
          *(const bf16x8*)(Ao + (size_t)(mbase + row) * 512 + kb + c8);
      const float* gb = Wo + (size_t)(nbase + row) * 512 + kb + c8;
      float4 b0 = *(const float4*)gb;
      float4 b1 = *(const float4*)(gb + 4);
      bf16x8 pb;
      pb[0] = (short)f2bf(b0.x); pb[1] = (short)f2bf(b0.y);
      pb[2] = (short)f2bf(b0.z); pb[3] = (short)f2bf(b0.w);
      pb[4] = (short)f2bf(b1.x); pb[5] = (short)f2bf(b1.y);
      pb[6] = (short)f2bf(b1.z); pb[7] = (short)f2bf(b1.w);
      *(bf16x8*)&Bs[row][c8] = pb;
    }
    __syncthreads();
#pragma unroll
    for (int kk = 0; kk < 64; kk += 32) {
      bf16x8 af[4], bfr[4];
#pragma unroll
      for (int mi = 0; mi < 4; ++mi)
        af[mi] = *(const bf16x8*)&As[wr * 64 + mi * 16 + (lane & 15)][kk + (lane >> 4) * 8];
#pragma unroll
      for (int ni = 0; ni < 4; ++ni)
        bfr[ni] = *(const bf16x8*)&Bs[wc * 64 + ni * 16 + (lane & 15)][kk + (lane >> 4) * 8];
#pragma unroll
      for (int mi = 0; mi < 4; ++mi)
#pragma unroll
        for (int ni = 0; ni < 4; ++ni)
          acc[mi][ni] = MFMA16(af[mi], bfr[ni], acc[mi][ni]);
    }
  }

#pragma unroll
  for (int ni = 0; ni < 4; ++ni) {
    int n = nbase + wc * 64 + ni * 16 + (lane & 15);
    float bv_ = bo[n];
#pragma unroll
    for (int mi = 0; mi < 4; ++mi) {
#pragma unroll
      for (int i = 0; i < 4; ++i) {
        int m = mbase + wr * 64 + mi * 16 + (lane >> 4) * 4 + i;
        outp[(size_t)m * 512 + n] = acc[mi][ni][i] + bv_;
      }
    }
  }
}

// ---------------------------------------------------------------------------
extern "C" void kernel_launch(void* const* d_in, const int* in_sizes, int n_in,
                              void* d_out, int out_size, void* d_ws, size_t ws_size,
                              hipStream_t stream) {
  const float* q_in = (const float*)d_in[0];
  const float* k_in = (const float*)d_in[1];
  const float* v_in = (const float*)d_in[2];
  const float* Wq = (const float*)d_in[3];
  const float* bq = (const float*)d_in[4];
  const float* Wk = (const float*)d_in[5];
  const float* bk = (const float*)d_in[6];
  const float* Wv = (const float*)d_in[7];
  const float* bv = (const float*)d_in[8];
  const float* Wo = (const float*)d_in[9];
  const float* bo = (const float*)d_in[10];

  float* out0 = (float*)d_out;                          // [B,S,D] f32
  float* attn = out0 + (size_t)4 * 2048 * 512;          // [B,H,S,S] f32

  unsigned short* ws = (unsigned short*)d_ws;
  const size_t SEG = (size_t)4 * 2048 * 512;
  unsigned short* q_ws  = ws;
  unsigned short* k_ws  = ws + SEG;
  unsigned short* vt_ws = ws + 2 * SEG;
  unsigned short* o_ws  = ws + 3 * SEG;
  float* rinv_g = (float*)(ws + 4 * SEG);               // [32][2048] f32

  dim3 g1(64, 4, 3);
  k_proj_qkv<<<g1, 256, 0, stream>>>(q_in, k_in, v_in, Wq, bq, Wk, bk, Wv, bv,
                                     q_ws, k_ws, vt_ws);
  dim3 g2(128, 32);
  k_attn_o<<<g2, 512, 0, stream>>>(q_ws, k_ws, vt_ws, o_ws, rinv_g);
  dim3 g3(64, 4);
  k_proj_out<<<g3, 256, 0, stream>>>(o_ws, Wo, bo, out0);
  dim3 g4(128, 32);
  k_attn_wr<<<g4, 256, 0, stream>>>(q_ws, k_ws, rinv_g, attn);
}

// Round 10
// 285.619 us; speedup vs baseline: 1.8867x; 1.8867x over previous
//
#include <hip/hip_runtime.h>
#include <hip/hip_bf16.h>
#include <stdint.h>

// MHA forward: B=4, S=2048, D=512, H=8, HD=64. f32 in/out, bf16 MFMA internally.
// out0 = out [B,S,D] f32, out1 = attn [B,H,S,S] f32 (concatenated in d_out).
// k_attn: Q-block 128 rows (8 waves x 16), two kv-sweeps:
//   pass A: staged K (dbuf) -> QK^T+exp+rowsum -> rv in regs (per wave).
//   pass B: staged K+V (dbuf) -> QK^T again -> normalized P -> PV + nt stores.

typedef __attribute__((ext_vector_type(8))) short bf16x8;
typedef __attribute__((ext_vector_type(4))) short bf16x4;
typedef __attribute__((ext_vector_type(4))) float f32x4;

#define MFMA16(a, b, c) __builtin_amdgcn_mfma_f32_16x16x32_bf16((a), (b), (c), 0, 0, 0)

__device__ __forceinline__ unsigned short f2bf(float f) {
  unsigned u = __float_as_uint(f);
  u += 0x7FFFu + ((u >> 16) & 1u);   // RNE
  return (unsigned short)(u >> 16);
}
__device__ __forceinline__ float bf2f(unsigned short u) {
  return __uint_as_float(((unsigned)u) << 16);
}

// ---------------------------------------------------------------------------
// Kernel 1: fused QKV projection. z = 0,1,2 -> q,k,v.
// q,k written as [B,H,S,HD] bf16; v written transposed [B,H,HD,S] bf16.
// ---------------------------------------------------------------------------
__global__ __launch_bounds__(256) void k_proj_qkv(
    const float* __restrict__ q_in, const float* __restrict__ k_in,
    const float* __restrict__ v_in,
    const float* __restrict__ Wq, const float* __restrict__ bq,
    const float* __restrict__ Wk, const float* __restrict__ bk,
    const float* __restrict__ Wv, const float* __restrict__ bv,
    unsigned short* __restrict__ q_ws, unsigned short* __restrict__ k_ws,
    unsigned short* __restrict__ vt_ws)
{
  const int z = blockIdx.z;
  const float* X    = (z == 0) ? q_in : (z == 1) ? k_in : v_in;
  const float* W    = (z == 0) ? Wq   : (z == 1) ? Wk   : Wv;
  const float* bias = (z == 0) ? bq   : (z == 1) ? bk   : bv;
  unsigned short* out = (z == 0) ? q_ws : (z == 1) ? k_ws : vt_ws;

  __shared__ unsigned short As[128][72];
  __shared__ unsigned short Bs[128][72];

  const int t = threadIdx.x;
  const int lane = t & 63;
  const int w = t >> 6;
  const int wr = w >> 1, wc = w & 1;
  const int mbase = blockIdx.x * 128;
  const int nbase = blockIdx.y * 128;

  f32x4 acc[4][4] = {};

  for (int kb = 0; kb < 512; kb += 64) {
    __syncthreads();
#pragma unroll
    for (int i = 0; i < 4; ++i) {
      int chunk = i * 256 + t;
      int row = chunk >> 3;
      int c8 = (chunk & 7) * 8;
      const float* ga = X + (size_t)(mbase + row) * 512 + kb + c8;
      float4 a0 = *(const float4*)ga;
      float4 a1 = *(const float4*)(ga + 4);
      bf16x8 pa;
      pa[0] = (short)f2bf(a0.x); pa[1] = (short)f2bf(a0.y);
      pa[2] = (short)f2bf(a0.z); pa[3] = (short)f2bf(a0.w);
      pa[4] = (short)f2bf(a1.x); pa[5] = (short)f2bf(a1.y);
      pa[6] = (short)f2bf(a1.z); pa[7] = (short)f2bf(a1.w);
      *(bf16x8*)&As[row][c8] = pa;
      const float* gb = W + (size_t)(nbase + row) * 512 + kb + c8;
      float4 b0 = *(const float4*)gb;
      float4 b1 = *(const float4*)(gb + 4);
      bf16x8 pb;
      pb[0] = (short)f2bf(b0.x); pb[1] = (short)f2bf(b0.y);
      pb[2] = (short)f2bf(b0.z); pb[3] = (short)f2bf(b0.w);
      pb[4] = (short)f2bf(b1.x); pb[5] = (short)f2bf(b1.y);
      pb[6] = (short)f2bf(b1.z); pb[7] = (short)f2bf(b1.w);
      *(bf16x8*)&Bs[row][c8] = pb;
    }
    __syncthreads();
#pragma unroll
    for (int kk = 0; kk < 64; kk += 32) {
      bf16x8 af[4], bfr[4];
#pragma unroll
      for (int mi = 0; mi < 4; ++mi)
        af[mi] = *(const bf16x8*)&As[wr * 64 + mi * 16 + (lane & 15)][kk + (lane >> 4) * 8];
#pragma unroll
      for (int ni = 0; ni < 4; ++ni)
        bfr[ni] = *(const bf16x8*)&Bs[wc * 64 + ni * 16 + (lane & 15)][kk + (lane >> 4) * 8];
#pragma unroll
      for (int mi = 0; mi < 4; ++mi)
#pragma unroll
        for (int ni = 0; ni < 4; ++ni)
          acc[mi][ni] = MFMA16(af[mi], bfr[ni], acc[mi][ni]);
    }
  }

#pragma unroll
  for (int ni = 0; ni < 4; ++ni) {
    int n = nbase + wc * 64 + ni * 16 + (lane & 15);
    float bv_ = bias[n];
    int h = n >> 6, hd = n & 63;
#pragma unroll
    for (int mi = 0; mi < 4; ++mi) {
#pragma unroll
      for (int i = 0; i < 4; ++i) {
        int m = mbase + wr * 64 + mi * 16 + (lane >> 4) * 4 + i;
        int b_ = m >> 11, s = m & 2047;
        float val = acc[mi][ni][i] + bv_;
        size_t off;
        if (z < 2) off = ((size_t)(b_ * 8 + h) * 2048 + s) * 64 + hd;      // [B,H,S,HD]
        else       off = ((size_t)(b_ * 8 + h) * 64 + hd) * 2048 + s;      // [B,H,HD,S]
        out[off] = f2bf(val);
      }
    }
  }
}

// ---------------------------------------------------------------------------
// Kernel 2: attention. Block = (b,h) x 128 q-rows, 8 waves (512 thr).
// Wave w owns q-rows [qbase + w*16, +16) and sweeps ALL kv (chunks of 64).
// Swapped QK^T: mfma(K,Q) -> lane (lo=q,hi) holds 4 consecutive kv per tile.
// K/V staged via LDS (coalesced, double-buffered, stride-72 rows = proven
// 0-conflict pattern). Denominator = in-wave shuffle (no cross-wave reduce).
// ---------------------------------------------------------------------------
__global__ __launch_bounds__(512, 4) void k_attn(
    const unsigned short* __restrict__ q_ws, const unsigned short* __restrict__ k_ws,
    const unsigned short* __restrict__ vt_ws, unsigned short* __restrict__ o_ws,
    float* __restrict__ attn_out)
{
  __shared__ unsigned short Ks[2][64][72];   // 18432 B
  __shared__ unsigned short Vs[2][64][72];   // 18432 B

  const int t = threadIdx.x;
  const int lane = t & 63;
  const int w = t >> 6;            // 0..7
  const int lo = lane & 15;
  const int hi = lane >> 4;        // 0..3
  const int bh = blockIdx.y;       // 0..31
  const int qbase = blockIdx.x * 128;
  const int qw = qbase + w * 16;   // wave's q rows
  const size_t qk_base = (size_t)bh * 2048 * 64;

  // staging coords: thread stages one bf16x8 of K (and V in pass B)
  const int sr = t >> 3;           // 0..63
  const int sc = (t & 7) * 8;      // 0..56

  // Q fragments (B operand: col = q = lo, d = hi*8 + j)
  bf16x8 qf0 = *(const bf16x8*)(q_ws + qk_base + (size_t)(qw + lo) * 64 + hi * 8);
  bf16x8 qf1 = *(const bf16x8*)(q_ws + qk_base + (size_t)(qw + lo) * 64 + 32 + hi * 8);

  // ---------------- pass A: row sums ----------------
  float srow = 0.f;
  {
    bf16x8 gk = *(const bf16x8*)(k_ws + qk_base + (size_t)sr * 64 + sc);
    int p = 0;
    for (int c = 0; c < 32; ++c) {
      *(bf16x8*)&Ks[p][sr][sc] = gk;
      if (c < 31)
        gk = *(const bf16x8*)(k_ws + qk_base + (size_t)((c + 1) * 64 + sr) * 64 + sc);
      __syncthreads();
#pragma unroll
      for (int t2 = 0; t2 < 4; ++t2) {
        bf16x8 kf0 = *(const bf16x8*)&Ks[p][t2 * 16 + lo][hi * 8];
        bf16x8 kf1 = *(const bf16x8*)&Ks[p][t2 * 16 + lo][32 + hi * 8];
        f32x4 cv = {};
        cv = MFMA16(kf0, qf0, cv);
        cv = MFMA16(kf1, qf1, cv);
        srow += __expf(cv[0] * 0.125f) + __expf(cv[1] * 0.125f) +
                __expf(cv[2] * 0.125f) + __expf(cv[3] * 0.125f);
      }
      p ^= 1;
    }
  }
  srow += __shfl_xor(srow, 16, 64);
  srow += __shfl_xor(srow, 32, 64);
  const float rv = 1.0f / srow;    // valid for q = lo in all lanes

  __syncthreads();                 // pass A reads done before pass B overwrites

  // ---------------- pass B: PV + attn stores ----------------
  f32x4 o_acc[4] = {};             // [hdt]: rows q=qw+hi*4+i, col hd=hdt*16+lo
  {
    float* ao = attn_out + (size_t)bh * 2048 * 2048 +
                (size_t)(qw + lo) * 2048 + hi * 4;
    bf16x8 gk = *(const bf16x8*)(k_ws + qk_base + (size_t)sr * 64 + sc);
    bf16x8 gv = *(const bf16x8*)(vt_ws + (size_t)(bh * 64 + sr) * 2048 + sc);
    int p = 0;
    for (int c = 0; c < 32; ++c) {
      *(bf16x8*)&Ks[p][sr][sc] = gk;
      *(bf16x8*)&Vs[p][sr][sc] = gv;
      if (c < 31) {
        gk = *(const bf16x8*)(k_ws + qk_base + (size_t)((c + 1) * 64 + sr) * 64 + sc);
        gv = *(const bf16x8*)(vt_ws + (size_t)(bh * 64 + sr) * 2048 + (c + 1) * 64 + sc);
      }
      __syncthreads();

      unsigned pk[4][2];           // normalized bf16 pairs per t2-tile
#pragma unroll
      for (int t2 = 0; t2 < 4; ++t2) {
        bf16x8 kf0 = *(const bf16x8*)&Ks[p][t2 * 16 + lo][hi * 8];
        bf16x8 kf1 = *(const bf16x8*)&Ks[p][t2 * 16 + lo][32 + hi * 8];
        f32x4 cv = {};
        cv = MFMA16(kf0, qf0, cv);
        cv = MFMA16(kf1, qf1, cv);
        float n0 = __expf(cv[0] * 0.125f) * rv;
        float n1 = __expf(cv[1] * 0.125f) * rv;
        float n2 = __expf(cv[2] * 0.125f) * rv;
        float n3 = __expf(cv[3] * 0.125f) * rv;
        // attn store: f32x4, q-row = lo, kv = c*64 + t2*16 + hi*4
        f32x4 s; s[0] = n0; s[1] = n1; s[2] = n2; s[3] = n3;
        __builtin_nontemporal_store(s, (f32x4*)(ao + c * 64 + t2 * 16));
        pk[t2][0] = (unsigned)f2bf(n0) | ((unsigned)f2bf(n1) << 16);
        pk[t2][1] = (unsigned)f2bf(n2) | ((unsigned)f2bf(n3) << 16);
      }
      // PV: two K=32 MFMAs per hdt (ks=0: t2 0,1; ks=1: t2 2,3)
#pragma unroll
      for (int ks = 0; ks < 2; ++ks) {
        bf16x8 pa8;
        pa8[0] = (short)(pk[2 * ks][0] & 0xffffu);
        pa8[1] = (short)(pk[2 * ks][0] >> 16);
        pa8[2] = (short)(pk[2 * ks][1] & 0xffffu);
        pa8[3] = (short)(pk[2 * ks][1] >> 16);
        pa8[4] = (short)(pk[2 * ks + 1][0] & 0xffffu);
        pa8[5] = (short)(pk[2 * ks + 1][0] >> 16);
        pa8[6] = (short)(pk[2 * ks + 1][1] & 0xffffu);
        pa8[7] = (short)(pk[2 * ks + 1][1] >> 16);
#pragma unroll
        for (int hdt = 0; hdt < 4; ++hdt) {
          bf16x4 v4a = *(const bf16x4*)&Vs[p][hdt * 16 + lo][ks * 32 + hi * 4];
          bf16x4 v4b = *(const bf16x4*)&Vs[p][hdt * 16 + lo][ks * 32 + 16 + hi * 4];
          bf16x8 vb8;
          vb8[0] = v4a[0]; vb8[1] = v4a[1]; vb8[2] = v4a[2]; vb8[3] = v4a[3];
          vb8[4] = v4b[0]; vb8[5] = v4b[1]; vb8[6] = v4b[2]; vb8[7] = v4b[3];
          o_acc[hdt] = MFMA16(pa8, vb8, o_acc[hdt]);
        }
      }
      p ^= 1;
    }
  }

  // ---------------- O write (already normalized) ----------------
  {
    const int b_ = bh >> 3, h = bh & 7;
#pragma unroll
    for (int hdt = 0; hdt < 4; ++hdt)
#pragma unroll
      for (int i = 0; i < 4; ++i) {
        int q = qw + hi * 4 + i;
        o_ws[((size_t)(b_ * 2048) + q) * 512 + h * 64 + hdt * 16 + lo] =
            f2bf(o_acc[hdt][i]);
      }
  }
}

// ---------------------------------------------------------------------------
// Kernel 3: output projection, f32 out.
// ---------------------------------------------------------------------------
__global__ __launch_bounds__(256) void k_proj_out(
    const unsigned short* __restrict__ Ao, const float* __restrict__ Wo,
    const float* __restrict__ bo, float* __restrict__ outp)
{
  __shared__ unsigned short As[128][72];
  __shared__ unsigned short Bs[128][72];

  const int t = threadIdx.x;
  const int lane = t & 63;
  const int w = t >> 6;
  const int wr = w >> 1, wc = w & 1;
  const int mbase = blockIdx.x * 128;
  const int nbase = blockIdx.y * 128;

  f32x4 acc[4][4] = {};

  for (int kb = 0; kb < 512; kb += 64) {
    __syncthreads();
#pragma unroll
    for (int i = 0; i < 4; ++i) {
      int chunk = i * 256 + t;
      int row = chunk >> 3;
      int c8 = (chunk & 7) * 8;
      *(bf16x8*)&As[row][c8] =
          *(const bf16x8*)(Ao + (size_t)(mbase + row) * 512 + kb + c8);
      const float* gb = Wo + (size_t)(nbase + row) * 512 + kb + c8;
      float4 b0 = *(const float4*)gb;
      float4 b1 = *(const float4*)(gb + 4);
      bf16x8 pb;
      pb[0] = (short)f2bf(b0.x); pb[1] = (short)f2bf(b0.y);
      pb[2] = (short)f2bf(b0.z); pb[3] = (short)f2bf(b0.w);
      pb[4] = (short)f2bf(b1.x); pb[5] = (short)f2bf(b1.y);
      pb[6] = (short)f2bf(b1.z); pb[7] = (short)f2bf(b1.w);
      *(bf16x8*)&Bs[row][c8] = pb;
    }
    __syncthreads();
#pragma unroll
    for (int kk = 0; kk < 64; kk += 32) {
      bf16x8 af[4], bfr[4];
#pragma unroll
      for (int mi = 0; mi < 4; ++mi)
        af[mi] = *(const bf16x8*)&As[wr * 64 + mi * 16 + (lane & 15)][kk + (lane >> 4) * 8];
#pragma unroll
      for (int ni = 0; ni < 4; ++ni)
        bfr[ni] = *(const bf16x8*)&Bs[wc * 64 + ni * 16 + (lane & 15)][kk + (lane >> 4) * 8];
#pragma unroll
      for (int mi = 0; mi < 4; ++mi)
#pragma unroll
        for (int ni = 0; ni < 4; ++ni)
          acc[mi][ni] = MFMA16(af[mi], bfr[ni], acc[mi][ni]);
    }
  }

#pragma unroll
  for (int ni = 0; ni < 4; ++ni) {
    int n = nbase + wc * 64 + ni * 16 + (lane & 15);
    float bv_ = bo[n];
#pragma unroll
    for (int mi = 0; mi < 4; ++mi) {
#pragma unroll
      for (int i = 0; i < 4; ++i) {
        int m = mbase + wr * 64 + mi * 16 + (lane >> 4) * 4 + i;
        outp[(size_t)m * 512 + n] = acc[mi][ni][i] + bv_;
      }
    }
  }
}

// ---------------------------------------------------------------------------
extern "C" void kernel_launch(void* const* d_in, const int* in_sizes, int n_in,
                              void* d_out, int out_size, void* d_ws, size_t ws_size,
                              hipStream_t stream) {
  const float* q_in = (const float*)d_in[0];
  const float* k_in = (const float*)d_in[1];
  const float* v_in = (const float*)d_in[2];
  const float* Wq = (const float*)d_in[3];
  const float* bq = (const float*)d_in[4];
  const float* Wk = (const float*)d_in[5];
  const float* bk = (const float*)d_in[6];
  const float* Wv = (const float*)d_in[7];
  const float* bv = (const float*)d_in[8];
  const float* Wo = (const float*)d_in[9];
  const float* bo = (const float*)d_in[10];

  float* out0 = (float*)d_out;                          // [B,S,D] f32
  float* attn = out0 + (size_t)4 * 2048 * 512;          // [B,H,S,S] f32

  unsigned short* ws = (unsigned short*)d_ws;
  const size_t SEG = (size_t)4 * 2048 * 512;
  unsigned short* q_ws  = ws;
  unsigned short* k_ws  = ws + SEG;
  unsigned short* vt_ws = ws + 2 * SEG;
  unsigned short* o_ws  = ws + 3 * SEG;

  dim3 g1(64, 4, 3);
  k_proj_qkv<<<g1, 256, 0, stream>>>(q_in, k_in, v_in, Wq, bq, Wk, bk, Wv, bv,
                                     q_ws, k_ws, vt_ws);
  dim3 g2(16, 32);
  k_attn<<<g2, 512, 0, stream>>>(q_ws, k_ws, vt_ws, o_ws, attn);
  dim3 g3(64, 4);
  k_proj_out<<<g3, 256, 0, stream>>>(o_ws, Wo, bo, out0);
}

// Round 11
// 254.304 us; speedup vs baseline: 2.1190x; 1.1231x over previous
//
#include <hip/hip_runtime.h>
#include <hip/hip_bf16.h>
#include <stdint.h>

// MHA forward: B=4, S=2048, D=512, H=8, HD=64. f32 in/out, bf16 MFMA internally.
// out0 = out [B,S,D] f32, out1 = attn [B,H,S,S] f32 (concatenated in d_out).
// k_attn: Q-block 64 rows (4 waves x 16), grid 1024, 4 blocks/CU. Two kv-
// sweeps: pass A (K staged dbuf -> QK^T+exp+rowsum -> rv), pass B (K+V staged
// -> QK^T -> normalized P -> nt attn stores + PV MFMA).

typedef __attribute__((ext_vector_type(8))) short bf16x8;
typedef __attribute__((ext_vector_type(4))) short bf16x4;
typedef __attribute__((ext_vector_type(4))) float f32x4;

#define MFMA16(a, b, c) __builtin_amdgcn_mfma_f32_16x16x32_bf16((a), (b), (c), 0, 0, 0)

__device__ __forceinline__ unsigned short f2bf(float f) {
  unsigned u = __float_as_uint(f);
  u += 0x7FFFu + ((u >> 16) & 1u);   // RNE
  return (unsigned short)(u >> 16);
}
__device__ __forceinline__ float bf2f(unsigned short u) {
  return __uint_as_float(((unsigned)u) << 16);
}

// ---------------------------------------------------------------------------
// Kernel 1: fused QKV projection. z = 0,1,2 -> q,k,v.
// q,k written as [B,H,S,HD] bf16; v written transposed [B,H,HD,S] bf16.
// ---------------------------------------------------------------------------
__global__ __launch_bounds__(256) void k_proj_qkv(
    const float* __restrict__ q_in, const float* __restrict__ k_in,
    const float* __restrict__ v_in,
    const float* __restrict__ Wq, const float* __restrict__ bq,
    const float* __restrict__ Wk, const float* __restrict__ bk,
    const float* __restrict__ Wv, const float* __restrict__ bv,
    unsigned short* __restrict__ q_ws, unsigned short* __restrict__ k_ws,
    unsigned short* __restrict__ vt_ws)
{
  const int z = blockIdx.z;
  const float* X    = (z == 0) ? q_in : (z == 1) ? k_in : v_in;
  const float* W    = (z == 0) ? Wq   : (z == 1) ? Wk   : Wv;
  const float* bias = (z == 0) ? bq   : (z == 1) ? bk   : bv;
  unsigned short* out = (z == 0) ? q_ws : (z == 1) ? k_ws : vt_ws;

  __shared__ unsigned short As[128][72];
  __shared__ unsigned short Bs[128][72];

  const int t = threadIdx.x;
  const int lane = t & 63;
  const int w = t >> 6;
  const int wr = w >> 1, wc = w & 1;
  const int mbase = blockIdx.x * 128;
  const int nbase = blockIdx.y * 128;

  f32x4 acc[4][4] = {};

  for (int kb = 0; kb < 512; kb += 64) {
    __syncthreads();
#pragma unroll
    for (int i = 0; i < 4; ++i) {
      int chunk = i * 256 + t;
      int row = chunk >> 3;
      int c8 = (chunk & 7) * 8;
      const float* ga = X + (size_t)(mbase + row) * 512 + kb + c8;
      float4 a0 = *(const float4*)ga;
      float4 a1 = *(const float4*)(ga + 4);
      bf16x8 pa;
      pa[0] = (short)f2bf(a0.x); pa[1] = (short)f2bf(a0.y);
      pa[2] = (short)f2bf(a0.z); pa[3] = (short)f2bf(a0.w);
      pa[4] = (short)f2bf(a1.x); pa[5] = (short)f2bf(a1.y);
      pa[6] = (short)f2bf(a1.z); pa[7] = (short)f2bf(a1.w);
      *(bf16x8*)&As[row][c8] = pa;
      const float* gb = W + (size_t)(nbase + row) * 512 + kb + c8;
      float4 b0 = *(const float4*)gb;
      float4 b1 = *(const float4*)(gb + 4);
      bf16x8 pb;
      pb[0] = (short)f2bf(b0.x); pb[1] = (short)f2bf(b0.y);
      pb[2] = (short)f2bf(b0.z); pb[3] = (short)f2bf(b0.w);
      pb[4] = (short)f2bf(b1.x); pb[5] = (short)f2bf(b1.y);
      pb[6] = (short)f2bf(b1.z); pb[7] = (short)f2bf(b1.w);
      *(bf16x8*)&Bs[row][c8] = pb;
    }
    __syncthreads();
#pragma unroll
    for (int kk = 0; kk < 64; kk += 32) {
      bf16x8 af[4], bfr[4];
#pragma unroll
      for (int mi = 0; mi < 4; ++mi)
        af[mi] = *(const bf16x8*)&As[wr * 64 + mi * 16 + (lane & 15)][kk + (lane >> 4) * 8];
#pragma unroll
      for (int ni = 0; ni < 4; ++ni)
        bfr[ni] = *(const bf16x8*)&Bs[wc * 64 + ni * 16 + (lane & 15)][kk + (lane >> 4) * 8];
#pragma unroll
      for (int mi = 0; mi < 4; ++mi)
#pragma unroll
        for (int ni = 0; ni < 4; ++ni)
          acc[mi][ni] = MFMA16(af[mi], bfr[ni], acc[mi][ni]);
    }
  }

#pragma unroll
  for (int ni = 0; ni < 4; ++ni) {
    int n = nbase + wc * 64 + ni * 16 + (lane & 15);
    float bv_ = bias[n];
    int h = n >> 6, hd = n & 63;
#pragma unroll
    for (int mi = 0; mi < 4; ++mi) {
#pragma unroll
      for (int i = 0; i < 4; ++i) {
        int m = mbase + wr * 64 + mi * 16 + (lane >> 4) * 4 + i;
        int b_ = m >> 11, s = m & 2047;
        float val = acc[mi][ni][i] + bv_;
        size_t off;
        if (z < 2) off = ((size_t)(b_ * 8 + h) * 2048 + s) * 64 + hd;      // [B,H,S,HD]
        else       off = ((size_t)(b_ * 8 + h) * 64 + hd) * 2048 + s;      // [B,H,HD,S]
        out[off] = f2bf(val);
      }
    }
  }
}

// ---------------------------------------------------------------------------
// Kernel 2: attention. Block = (b,h) x 64 q-rows, 4 waves (256 thr),
// grid (32, 32) = 1024 blocks -> 4 blocks/CU. Wave w owns q-rows
// [qbase + w*16, +16) and sweeps ALL kv (chunks of 64, double-buffered LDS).
// Swapped QK^T: mfma(K,Q) -> lane (lo=q,hi) holds 4 consecutive kv per tile.
// ---------------------------------------------------------------------------
__global__ __launch_bounds__(256, 4) void k_attn(
    const unsigned short* __restrict__ q_ws, const unsigned short* __restrict__ k_ws,
    const unsigned short* __restrict__ vt_ws, unsigned short* __restrict__ o_ws,
    float* __restrict__ attn_out)
{
  __shared__ unsigned short Ks[2][64][72];   // 18432 B
  __shared__ unsigned short Vs[2][64][72];   // 18432 B

  const int t = threadIdx.x;
  const int lane = t & 63;
  const int w = t >> 6;            // 0..3
  const int lo = lane & 15;
  const int hi = lane >> 4;        // 0..3
  const int bh = blockIdx.y;       // 0..31
  const int qbase = blockIdx.x * 64;
  const int qw = qbase + w * 16;   // wave's q rows
  const size_t qk_base = (size_t)bh * 2048 * 64;

  // staging coords: thread stages two bf16x8 per buffer per chunk
  // flat = t + i*256 in [0,1024): r = flat>>3 (0..63... wait 1024/8=128)
  // 64 rows x 8 col-chunks = 512 slots; i<2 -> flat in [0,512).
  // r = flat>>3 in [0,64), c8 = (flat&7)*8.

  // Q fragments (B operand: col = q = lo, d = hi*8 + j)
  bf16x8 qf0 = *(const bf16x8*)(q_ws + qk_base + (size_t)(qw + lo) * 64 + hi * 8);
  bf16x8 qf1 = *(const bf16x8*)(q_ws + qk_base + (size_t)(qw + lo) * 64 + 32 + hi * 8);

  // ---------------- pass A: row sums ----------------
  float srow = 0.f;
  {
    bf16x8 gk[2];
#pragma unroll
    for (int i = 0; i < 2; ++i) {
      int flat = t + i * 256;
      gk[i] = *(const bf16x8*)(k_ws + qk_base + (size_t)(flat >> 3) * 64 + (flat & 7) * 8);
    }
    int p = 0;
    for (int c = 0; c < 32; ++c) {
#pragma unroll
      for (int i = 0; i < 2; ++i) {
        int flat = t + i * 256;
        *(bf16x8*)&Ks[p][flat >> 3][(flat & 7) * 8] = gk[i];
      }
      if (c < 31) {
#pragma unroll
        for (int i = 0; i < 2; ++i) {
          int flat = t + i * 256;
          gk[i] = *(const bf16x8*)(k_ws + qk_base +
                                   (size_t)((c + 1) * 64 + (flat >> 3)) * 64 + (flat & 7) * 8);
        }
      }
      __syncthreads();
#pragma unroll
      for (int t2 = 0; t2 < 4; ++t2) {
        bf16x8 kf0 = *(const bf16x8*)&Ks[p][t2 * 16 + lo][hi * 8];
        bf16x8 kf1 = *(const bf16x8*)&Ks[p][t2 * 16 + lo][32 + hi * 8];
        f32x4 cv = {};
        cv = MFMA16(kf0, qf0, cv);
        cv = MFMA16(kf1, qf1, cv);
        srow += __expf(cv[0] * 0.125f) + __expf(cv[1] * 0.125f) +
                __expf(cv[2] * 0.125f) + __expf(cv[3] * 0.125f);
      }
      p ^= 1;
      __syncthreads();   // readers done before this buffer is overwritten next+1
    }
  }
  srow += __shfl_xor(srow, 16, 64);
  srow += __shfl_xor(srow, 32, 64);
  const float rv = 1.0f / srow;    // valid for q = lo in all lanes

  __syncthreads();                 // pass A reads done before pass B overwrites

  // ---------------- pass B: PV + attn stores ----------------
  f32x4 o_acc[4] = {};             // [hdt]: rows q=qw+hi*4+i, col hd=hdt*16+lo
  {
    float* ao = attn_out + (size_t)bh * 2048 * 2048 +
                (size_t)(qw + lo) * 2048 + hi * 4;
    bf16x8 gk[2], gv[2];
#pragma unroll
    for (int i = 0; i < 2; ++i) {
      int flat = t + i * 256;
      gk[i] = *(const bf16x8*)(k_ws + qk_base + (size_t)(flat >> 3) * 64 + (flat & 7) * 8);
      gv[i] = *(const bf16x8*)(vt_ws + (size_t)(bh * 64 + (flat >> 3)) * 2048 + (flat & 7) * 8);
    }
    int p = 0;
    for (int c = 0; c < 32; ++c) {
#pragma unroll
      for (int i = 0; i < 2; ++i) {
        int flat = t + i * 256;
        *(bf16x8*)&Ks[p][flat >> 3][(flat & 7) * 8] = gk[i];
        *(bf16x8*)&Vs[p][flat >> 3][(flat & 7) * 8] = gv[i];
      }
      if (c < 31) {
#pragma unroll
        for (int i = 0; i < 2; ++i) {
          int flat = t + i * 256;
          gk[i] = *(const bf16x8*)(k_ws + qk_base +
                                   (size_t)((c + 1) * 64 + (flat >> 3)) * 64 + (flat & 7) * 8);
          gv[i] = *(const bf16x8*)(vt_ws + (size_t)(bh * 64 + (flat >> 3)) * 2048 +
                                   (c + 1) * 64 + (flat & 7) * 8);
        }
      }
      __syncthreads();

      unsigned pk[4][2];           // normalized bf16 pairs per t2-tile
#pragma unroll
      for (int t2 = 0; t2 < 4; ++t2) {
        bf16x8 kf0 = *(const bf16x8*)&Ks[p][t2 * 16 + lo][hi * 8];
        bf16x8 kf1 = *(const bf16x8*)&Ks[p][t2 * 16 + lo][32 + hi * 8];
        f32x4 cv = {};
        cv = MFMA16(kf0, qf0, cv);
        cv = MFMA16(kf1, qf1, cv);
        float n0 = __expf(cv[0] * 0.125f) * rv;
        float n1 = __expf(cv[1] * 0.125f) * rv;
        float n2 = __expf(cv[2] * 0.125f) * rv;
        float n3 = __expf(cv[3] * 0.125f) * rv;
        // attn store: f32x4, q-row = lo, kv = c*64 + t2*16 + hi*4
        f32x4 s; s[0] = n0; s[1] = n1; s[2] = n2; s[3] = n3;
        __builtin_nontemporal_store(s, (f32x4*)(ao + c * 64 + t2 * 16));
        pk[t2][0] = (unsigned)f2bf(n0) | ((unsigned)f2bf(n1) << 16);
        pk[t2][1] = (unsigned)f2bf(n2) | ((unsigned)f2bf(n3) << 16);
      }
      // PV: two K=32 MFMAs per hdt (ks=0: t2 0,1; ks=1: t2 2,3)
#pragma unroll
      for (int ks = 0; ks < 2; ++ks) {
        bf16x8 pa8;
        pa8[0] = (short)(pk[2 * ks][0] & 0xffffu);
        pa8[1] = (short)(pk[2 * ks][0] >> 16);
        pa8[2] = (short)(pk[2 * ks][1] & 0xffffu);
        pa8[3] = (short)(pk[2 * ks][1] >> 16);
        pa8[4] = (short)(pk[2 * ks + 1][0] & 0xffffu);
        pa8[5] = (short)(pk[2 * ks + 1][0] >> 16);
        pa8[6] = (short)(pk[2 * ks + 1][1] & 0xffffu);
        pa8[7] = (short)(pk[2 * ks + 1][1] >> 16);
#pragma unroll
        for (int hdt = 0; hdt < 4; ++hdt) {
          bf16x4 v4a = *(const bf16x4*)&Vs[p][hdt * 16 + lo][ks * 32 + hi * 4];
          bf16x4 v4b = *(const bf16x4*)&Vs[p][hdt * 16 + lo][ks * 32 + 16 + hi * 4];
          bf16x8 vb8;
          vb8[0] = v4a[0]; vb8[1] = v4a[1]; vb8[2] = v4a[2]; vb8[3] = v4a[3];
          vb8[4] = v4b[0]; vb8[5] = v4b[1]; vb8[6] = v4b[2]; vb8[7] = v4b[3];
          o_acc[hdt] = MFMA16(pa8, vb8, o_acc[hdt]);
        }
      }
      p ^= 1;
      __syncthreads();
    }
  }

  // ---------------- O write (already normalized) ----------------
  {
    const int b_ = bh >> 3, h = bh & 7;
#pragma unroll
    for (int hdt = 0; hdt < 4; ++hdt)
#pragma unroll
      for (int i = 0; i < 4; ++i) {
        int q = qw + hi * 4 + i;
        o_ws[((size_t)(b_ * 2048) + q) * 512 + h * 64 + hdt * 16 + lo] =
            f2bf(o_acc[hdt][i]);
      }
  }
}

// ---------------------------------------------------------------------------
// Kernel 3: output projection, f32 out.
// ---------------------------------------------------------------------------
__global__ __launch_bounds__(256) void k_proj_out(
    const unsigned short* __restrict__ Ao, const float* __restrict__ Wo,
    const float* __restrict__ bo, float* __restrict__ outp)
{
  __shared__ unsigned short As[128][72];
  __shared__ unsigned short Bs[128][72];

  const int t = threadIdx.x;
  const int lane = t & 63;
  const int w = t >> 6;
  const int wr = w >> 1, wc = w & 1;
  const int mbase = blockIdx.x * 128;
  const int nbase = blockIdx.y * 128;

  f32x4 acc[4][4] = {};

  for (int kb = 0; kb < 512; kb += 64) {
    __syncthreads();
#pragma unroll
    for (int i = 0; i < 4; ++i) {
      int chunk = i * 256 + t;
      int row = chunk >> 3;
      int c8 = (chunk & 7) * 8;
      *(bf16x8*)&As[row][c8] =
          *(const bf16x8*)(Ao + (size_t)(mbase + row) * 512 + kb + c8);
      const float* gb = Wo + (size_t)(nbase + row) * 512 + kb + c8;
      float4 b0 = *(const float4*)gb;
      float4 b1 = *(const float4*)(gb + 4);
      bf16x8 pb;
      pb[0] = (short)f2bf(b0.x); pb[1] = (short)f2bf(b0.y);
      pb[2] = (short)f2bf(b0.z); pb[3] = (short)f2bf(b0.w);
      pb[4] = (short)f2bf(b1.x); pb[5] = (short)f2bf(b1.y);
      pb[6] = (short)f2bf(b1.z); pb[7] = (short)f2bf(b1.w);
      *(bf16x8*)&Bs[row][c8] = pb;
    }
    __syncthreads();
#pragma unroll
    for (int kk = 0; kk < 64; kk += 32) {
      bf16x8 af[4], bfr[4];
#pragma unroll
      for (int mi = 0; mi < 4; ++mi)
        af[mi] = *(const bf16x8*)&As[wr * 64 + mi * 16 + (lane & 15)][kk + (lane >> 4) * 8];
#pragma unroll
      for (int ni = 0; ni < 4; ++ni)
        bfr[ni] = *(const bf16x8*)&Bs[wc * 64 + ni * 16 + (lane & 15)][kk + (lane >> 4) * 8];
#pragma unroll
      for (int mi = 0; mi < 4; ++mi)
#pragma unroll
        for (int ni = 0; ni < 4; ++ni)
          acc[mi][ni] = MFMA16(af[mi], bfr[ni], acc[mi][ni]);
    }
  }

#pragma unroll
  for (int ni = 0; ni < 4; ++ni) {
    int n = nbase + wc * 64 + ni * 16 + (lane & 15);
    float bv_ = bo[n];
#pragma unroll
    for (int mi = 0; mi < 4; ++mi) {
#pragma unroll
      for (int i = 0; i < 4; ++i) {
        int m = mbase + wr * 64 + mi * 16 + (lane >> 4) * 4 + i;
        outp[(size_t)m * 512 + n] = acc[mi][ni][i] + bv_;
      }
    }
  }
}

// ---------------------------------------------------------------------------
extern "C" void kernel_launch(void* const* d_in, const int* in_sizes, int n_in,
                              void* d_out, int out_size, void* d_ws, size_t ws_size,
                              hipStream_t stream) {
  const float* q_in = (const float*)d_in[0];
  const float* k_in = (const float*)d_in[1];
  const float* v_in = (const float*)d_in[2];
  const float* Wq = (const float*)d_in[3];
  const float* bq = (const float*)d_in[4];
  const float* Wk = (const float*)d_in[5];
  const float* bk = (const float*)d_in[6];
  const float* Wv = (const float*)d_in[7];
  const float* bv = (const float*)d_in[8];
  const float* Wo = (const float*)d_in[9];
  const float* bo = (const float*)d_in[10];

  float* out0 = (float*)d_out;                          // [B,S,D] f32
  float* attn = out0 + (size_t)4 * 2048 * 512;          // [B,H,S,S] f32

  unsigned short* ws = (unsigned short*)d_ws;
  const size_t SEG = (size_t)4 * 2048 * 512;
  unsigned short* q_ws  = ws;
  unsigned short* k_ws  = ws + SEG;
  unsigned short* vt_ws = ws + 2 * SEG;
  unsigned short* o_ws  = ws + 3 * SEG;

  dim3 g1(64, 4, 3);
  k_proj_qkv<<<g1, 256, 0, stream>>>(q_in, k_in, v_in, Wq, bq, Wk, bk, Wv, bv,
                                     q_ws, k_ws, vt_ws);
  dim3 g2(32, 32);
  k_attn<<<g2, 256, 0, stream>>>(q_ws, k_ws, vt_ws, o_ws, attn);
  dim3 g3(64, 4);
  k_proj_out<<<g3, 256, 0, stream>>>(o_ws, Wo, bo, out0);
}